// Round 3
// baseline (91.997 us; speedup 1.0000x reference)
//
#include <hip/hip_runtime.h>
#include <math.h>

#define BROWS 8192
#define WDIM 256
#define NT 3             // 128x128 tile pairs: t0=(0,0), t1=(0,1), t2=(1,1)
#define CHUNKS 256       // 256 * 32 rows = 8192 exactly
#define CHUNK_ROWS 32
#define TILE_ELEMS 16384 // 128*128
#define FIN_BLOCKS 192   // 192*256 = 49152 = NT*TILE_ELEMS

// ws layout (floats): [0..255] colsum | [256] lossacc | [257] done | [512..] partials (50.3 MB)

// ---------------------------------------------------- Gram partials + colsum
// grid = (NT, CHUNKS), block = 256. 8x8 accumulators/thread: 1 LDS byte/MAC
// (vs 2 in the 4x4 version) -- DS pipe was the binding resource.
__global__ __launch_bounds__(256)
void gram_kernel(const float* __restrict__ E, float* __restrict__ ws) {
    float* colsum   = ws;
    float* partials = ws + 512;

    const int t = blockIdx.x;                 // 0..2
    const int c = blockIdx.y;                 // 0..255
    const int ti = (t == 2) ? 1 : 0;
    const int tj = (t == 0) ? 0 : 1;
    const bool diag = (t != 1);               // block-uniform
    const int tid = threadIdx.x;
    const int tx = tid & 15, ty = tid >> 4;

    __shared__ __align__(16) float lds[9216]; // As[2][16][128] | Bs[2][16][128] | Cs[8][128]
    float* As = lds;
    float* Bs = lds + 4096;
    float* Cs = lds + 8192;

    const int row0 = c * CHUNK_ROWS;
    const float* Ea = E + ti * 128;
    const float* Eb = E + tj * 128;

    // Load both 16-row stages up front (no mid-kernel global waits).
    float4 ga[4], gb[4];
    #pragma unroll
    for (int s = 0; s < 2; ++s)
        #pragma unroll
        for (int i = 0; i < 2; ++i) {
            const int p = tid + i * 256;                 // float4 index in stage
            const int r = p >> 5, c4 = p & 31;           // 32 float4 per 128-col row
            const size_t gr = (size_t)(row0 + s * 16 + r) * WDIM;
            ga[s * 2 + i] = *(const float4*)(Ea + gr + c4 * 4);
            if (!diag) gb[s * 2 + i] = *(const float4*)(Eb + gr + c4 * 4);
        }

    #pragma unroll
    for (int s = 0; s < 2; ++s)
        #pragma unroll
        for (int i = 0; i < 2; ++i) {
            const int p = tid + i * 256;
            const int r = p >> 5, c4 = p & 31;
            *(float4*)&As[s * 2048 + r * 128 + c4 * 4] = ga[s * 2 + i];
            if (!diag) *(float4*)&Bs[s * 2048 + r * 128 + c4 * 4] = gb[s * 2 + i];
        }
    if (diag) {
        // column-sum partials: this thread's 4 float4s all cover cols c4*4..+3
        float4 cs;
        cs.x = ga[0].x + ga[1].x + ga[2].x + ga[3].x;
        cs.y = ga[0].y + ga[1].y + ga[2].y + ga[3].y;
        cs.z = ga[0].z + ga[1].z + ga[2].z + ga[3].z;
        cs.w = ga[0].w + ga[1].w + ga[2].w + ga[3].w;
        *(float4*)&Cs[(tid >> 5) * 128 + (tid & 31) * 4] = cs;
    }

    __syncthreads();                           // the only barrier in this kernel

    if (diag && tid < 128) {
        float s = 0.f;
        #pragma unroll
        for (int m = 0; m < 8; ++m) s += Cs[m * 128 + tid];
        atomicAdd(&colsum[ti * 128 + tid], s); // no-return atomic: fire-and-forget,
                                               // hidden under the k-loop below
    }

    const float* Bp = diag ? As : Bs;          // diagonal tiles: B slice == A slice
    float acc[8][8];
    #pragma unroll
    for (int ii = 0; ii < 8; ++ii)
        #pragma unroll
        for (int jj = 0; jj < 8; ++jj) acc[ii][jj] = 0.f;

    #pragma unroll
    for (int s2 = 0; s2 < 2; ++s2) {
        const int sb = s2 * 2048;
        #pragma unroll 4
        for (int k = 0; k < 16; ++k) {
            // fragments split into two float4 groups 64 apart:
            // A: 4 unique addrs, 16-way broadcast (free); B: 2-way/bank (free, m136)
            const float4 a0 = *(const float4*)&As[sb + k * 128 + ty * 4];
            const float4 a1 = *(const float4*)&As[sb + k * 128 + 64 + ty * 4];
            const float4 b0 = *(const float4*)&Bp[sb + k * 128 + tx * 4];
            const float4 b1 = *(const float4*)&Bp[sb + k * 128 + 64 + tx * 4];
            const float av[8] = {a0.x, a0.y, a0.z, a0.w, a1.x, a1.y, a1.z, a1.w};
            const float bv[8] = {b0.x, b0.y, b0.z, b0.w, b1.x, b1.y, b1.z, b1.w};
            #pragma unroll
            for (int ii = 0; ii < 8; ++ii)
                #pragma unroll
                for (int jj = 0; jj < 8; ++jj)
                    acc[ii][jj] = fmaf(av[ii], bv[jj], acc[ii][jj]);
        }
    }

    float* dst = partials + (size_t)(c * NT + t) * TILE_ELEMS;
    #pragma unroll
    for (int ri = 0; ri < 2; ++ri)
        #pragma unroll
        for (int ii = 0; ii < 4; ++ii)
            #pragma unroll
            for (int ci = 0; ci < 2; ++ci) {
                const int row = ri * 64 + ty * 4 + ii;
                const int colg = ci * 64 + tx * 4;
                const float4 v = make_float4(acc[ri * 4 + ii][ci * 4 + 0],
                                             acc[ri * 4 + ii][ci * 4 + 1],
                                             acc[ri * 4 + ii][ci * 4 + 2],
                                             acc[ri * 4 + ii][ci * 4 + 3]);
                *(float4*)(dst + row * 128 + colg) = v;
            }
}

// ----------------------------------------------- finalize loss + sqrt fused
__global__ __launch_bounds__(256)
void finalize_kernel(float* __restrict__ ws, float* __restrict__ out) {
    const float* colsum   = ws;
    float* lossacc        = ws + 256;
    unsigned* done        = (unsigned*)(ws + 257);
    const float* partials = ws + 512;

    const int e = blockIdx.x * 256 + threadIdx.x;   // 0..49151
    const int t = e >> 14;                          // 16384 elements per tile
    const int local = e & 16383;
    const int ti = (t == 2) ? 1 : 0;
    const int tj = (t == 0) ? 0 : 1;
    const int i = ti * 128 + (local >> 7);
    const int j = tj * 128 + (local & 127);

    float g = 0.f;
    #pragma unroll 32
    for (int c = 0; c < CHUNKS; ++c)
        g += partials[(size_t)(c * NT + t) * TILE_ELEMS + local];

    const float inv_b = 1.0f / (float)BROWS;
    const float mi = colsum[i] * inv_b;
    const float mj = colsum[j] * inv_b;
    const float diff = g * inv_b - mi * mj - ((i == j) ? 1.0f : 0.0f);
    float v = ((t == 1) ? 2.0f : 1.0f) * diff * diff;

    #pragma unroll
    for (int o = 32; o > 0; o >>= 1) v += __shfl_down(v, o, 64);

    __shared__ float red[4];
    if ((threadIdx.x & 63) == 0) red[threadIdx.x >> 6] = v;
    __syncthreads();
    if (threadIdx.x == 0) {
        const float s = red[0] + red[1] + red[2] + red[3];
        atomicAdd(lossacc, s);
        __threadfence();
        const unsigned old = atomicAdd(done, 1u);
        if (old == FIN_BLOCKS - 1) {
            __threadfence();
            const float total = atomicAdd(lossacc, 0.0f);  // atomic read
            out[0] = sqrtf(total);
        }
    }
}

// ---------------------------------------------------------------------- host
extern "C" void kernel_launch(void* const* d_in, const int* in_sizes, int n_in,
                              void* d_out, int out_size, void* d_ws, size_t ws_size,
                              hipStream_t stream) {
    const float* E = (const float*)d_in[0];
    // d_in[1] (label) is unused by the reference math.
    float* out = (float*)d_out;
    float* ws = (float*)d_ws;

    hipMemsetAsync(d_ws, 0, 512 * sizeof(float), stream);  // colsum + lossacc + done
    gram_kernel<<<dim3(NT, CHUNKS), 256, 0, stream>>>(E, ws);
    finalize_kernel<<<FIN_BLOCKS, 256, 0, stream>>>(ws, out);
}

// Round 5
// 83.428 us; speedup vs baseline: 1.1027x; 1.1027x over previous
//
#include <hip/hip_runtime.h>
#include <math.h>

typedef unsigned int uint32;
typedef unsigned short ushort16;
typedef __bf16 bf16x8 __attribute__((ext_vector_type(8)));
typedef float f32x16 __attribute__((ext_vector_type(16)));

#define BROWS 8192
#define WDIM 256
#define NT 3             // 128x128 tile pairs: t0=(0,0), t1=(0,1), t2=(1,1)
#define CHUNKS 64        // 64 * 128 = 8192 rows
#define CHUNK_K 128
#define TILE_ELEMS 16384
#define FIN_BLOCKS 192   // 192*256 = 49152 = NT*TILE_ELEMS

// ws float layout:
// [0 .. 8191]          colsum_part[32][256] (plain stores, no init needed)
// [8192]               lossacc   (zeroed by cast block 0)
// [8193]               done u32  (zeroed by cast block 0)
// [8448 .. +3145728)   partials  CHUNKS*NT*TILE_ELEMS (12.6 MB)
// [3154176 .. )        E_t bf16 [256 cols][8192 rows] (4 MB, 16B-aligned base)
#define WS_LOSS 8192
#define WS_DONE 8193
#define WS_PART 8448
#define WS_ET   3154176

__device__ __forceinline__ uint32 pack2bf(float lo, float hi) {
    uint32 a = __float_as_uint(lo), b = __float_as_uint(hi);
    a = (a + 0x7FFFu + ((a >> 16) & 1u)) >> 16;   // RNE fp32->bf16
    b = (b + 0x7FFFu + ((b >> 16) & 1u)) >> 16;
    return a | (b << 16);
}

// ------------------------------------ cast fp32 -> bf16, transpose, colsum
// grid (4 colgroups, 32 rowgroups), 256 threads. Tile: 64 cols x 256 rows.
__global__ __launch_bounds__(256)
void cast_t_kernel(const float* __restrict__ E, float* __restrict__ ws) {
    const int cg = blockIdx.x;            // 64-col group
    const int rg = blockIdx.y;            // 256-row group
    const int tid = threadIdx.x;
    __shared__ uint32 U[64 * 129];        // [col][rowpair], pad->2-way banks
    __shared__ float Cs[16 * 64];

    if (cg == 0 && rg == 0 && tid < 2) ws[WS_LOSS + tid] = 0.0f;

    const int c4 = tid & 15;              // float4-col within the 64
    const int rp = tid >> 4;              // rowpair base 0..15
    const float* Eb = E + (size_t)(rg * 256) * WDIM + cg * 64;

    float4 cs = make_float4(0.f, 0.f, 0.f, 0.f);
    #pragma unroll
    for (int p = 0; p < 8; ++p) {
        const int rpi = rp + 16 * p;      // rowpair 0..127
        const int r0 = 2 * rpi;
        const float4 fa = *(const float4*)(Eb + (size_t)r0 * WDIM + c4 * 4);
        const float4 fb = *(const float4*)(Eb + (size_t)(r0 + 1) * WDIM + c4 * 4);
        cs.x += fa.x + fb.x; cs.y += fa.y + fb.y;
        cs.z += fa.z + fb.z; cs.w += fa.w + fb.w;
        U[(c4 * 4 + 0) * 129 + rpi] = pack2bf(fa.x, fb.x);
        U[(c4 * 4 + 1) * 129 + rpi] = pack2bf(fa.y, fb.y);
        U[(c4 * 4 + 2) * 129 + rpi] = pack2bf(fa.z, fb.z);
        U[(c4 * 4 + 3) * 129 + rpi] = pack2bf(fa.w, fb.w);
    }
    *(float4*)&Cs[rp * 64 + c4 * 4] = cs;
    __syncthreads();

    if (tid < 64) {                       // fp32 colsum partial for this rowgroup
        float s = 0.f;
        #pragma unroll
        for (int r = 0; r < 16; ++r) s += Cs[r * 64 + tid];
        ws[rg * WDIM + cg * 64 + tid] = s;    // plain store, no init needed
    }

    uint32* Et = (uint32*)(ws + WS_ET);
    const int col = tid >> 2, sub = tid & 3;  // 4 threads per col
    // column = 4096 uint32 (8192 rows / 2); this block covers rowpairs
    // [rg*128, rg*128+128)  -- (was rg*64: the round-4 overlap bug)
    uint32* dstc = Et + (size_t)(cg * 64 + col) * 4096 + rg * 128 + sub * 32;
    const uint32* Uc = U + col * 129 + sub * 32;
    #pragma unroll
    for (int j = 0; j < 8; ++j) {
        uint4 v;
        v.x = Uc[4 * j + 0]; v.y = Uc[4 * j + 1];
        v.z = Uc[4 * j + 2]; v.w = Uc[4 * j + 3];
        *(uint4*)(dstc + 4 * j) = v;      // 16B-aligned
    }
}

// ------------------------------------------------ MFMA gram, zero LDS
// grid (NT, CHUNKS), 256 thr = 4 waves. Wave w: G-rows ti*128+32w..+32,
// all 128 cols of tj. Fragments loaded directly from k-contiguous E_t:
// one dwordx4 per lane per fragment. fp32 accumulation in AGPRs (exact).
__global__ __launch_bounds__(256)
void gram_kernel(float* __restrict__ ws) {
    const ushort16* Et = (const ushort16*)(ws + WS_ET);
    float* partials = ws + WS_PART;
    const int t = blockIdx.x, c = blockIdx.y;
    const int ti = (t == 2) ? 1 : 0;
    const int tj = (t == 0) ? 0 : 1;
    const int tid = threadIdx.x, w = tid >> 6, l = tid & 63;
    const int lm = l & 31;                // m/n index (lane&31 map)
    const int lk = (l >> 5) * 8;          // k offset (any k-perm cancels A vs B)
    const size_t CS = 8192;               // E_t column stride (u16)

    const ushort16* ap = Et + (size_t)(ti * 128 + w * 32 + lm) * CS + (size_t)c * CHUNK_K + lk;
    const ushort16* bp = Et + (size_t)(tj * 128 + lm) * CS + (size_t)c * CHUNK_K + lk;

    f32x16 acc[4];
    #pragma unroll
    for (int n = 0; n < 4; ++n)
        #pragma unroll
        for (int r = 0; r < 16; ++r) acc[n][r] = 0.f;

    #pragma unroll
    for (int s = 0; s < 8; ++s) {         // K = 128 = 8 steps of 16
        const int o = s * 16;
        const bf16x8 a  = *(const bf16x8*)(ap + o);
        const bf16x8 b0 = *(const bf16x8*)(bp + o);
        const bf16x8 b1 = *(const bf16x8*)(bp + 32 * CS + o);
        const bf16x8 b2 = *(const bf16x8*)(bp + 64 * CS + o);
        const bf16x8 b3 = *(const bf16x8*)(bp + 96 * CS + o);
        acc[0] = __builtin_amdgcn_mfma_f32_32x32x16_bf16(a, b0, acc[0], 0, 0, 0);
        acc[1] = __builtin_amdgcn_mfma_f32_32x32x16_bf16(a, b1, acc[1], 0, 0, 0);
        acc[2] = __builtin_amdgcn_mfma_f32_32x32x16_bf16(a, b2, acc[2], 0, 0, 0);
        acc[3] = __builtin_amdgcn_mfma_f32_32x32x16_bf16(a, b3, acc[3], 0, 0, 0);
    }

    // C/D layout (m74/m101 verified): col = lane&31, row = (r&3)+8*(r>>2)+4*(lane>>5)
    float* dst = partials + ((size_t)c * NT + t) * TILE_ELEMS;
    const int rbase = 32 * w + 4 * (l >> 5);
    #pragma unroll
    for (int n = 0; n < 4; ++n)
        #pragma unroll
        for (int r = 0; r < 16; ++r) {
            const int row = rbase + (r & 3) + 8 * (r >> 2);
            dst[row * 128 + n * 32 + lm] = acc[n][r];
        }
}

// ----------------------------------------------- finalize loss + sqrt fused
__global__ __launch_bounds__(256)
void finalize_kernel(float* __restrict__ ws, float* __restrict__ out) {
    __shared__ float mu[WDIM];
    __shared__ float red[4];
    const float* partials = ws + WS_PART;
    float* lossacc = ws + WS_LOSS;
    unsigned* done = (unsigned*)(ws + WS_DONE);
    const int tid = threadIdx.x;

    {   // reduce the 32 colsum partial slots -> mu
        float s = 0.f;
        #pragma unroll 8
        for (int rg = 0; rg < 32; ++rg) s += ws[rg * WDIM + tid];
        mu[tid] = s * (1.0f / (float)BROWS);
    }
    __syncthreads();

    const int e = blockIdx.x * 256 + tid;            // 0..49151
    const int t = e >> 14, local = e & 16383;
    const int ti = (t == 2) ? 1 : 0;
    const int tj = (t == 0) ? 0 : 1;
    const int i = ti * 128 + (local >> 7);
    const int j = tj * 128 + (local & 127);

    float g = 0.f;
    #pragma unroll 8
    for (int c = 0; c < CHUNKS; ++c)
        g += partials[((size_t)c * NT + t) * TILE_ELEMS + local];

    const float diff = g * (1.0f / (float)BROWS) - mu[i] * mu[j] - ((i == j) ? 1.0f : 0.0f);
    float v = ((t == 1) ? 2.0f : 1.0f) * diff * diff;

    #pragma unroll
    for (int o = 32; o > 0; o >>= 1) v += __shfl_down(v, o, 64);
    if ((tid & 63) == 0) red[tid >> 6] = v;
    __syncthreads();
    if (tid == 0) {
        atomicAdd(lossacc, red[0] + red[1] + red[2] + red[3]);
        __threadfence();
        const unsigned old = atomicAdd(done, 1u);
        if (old == FIN_BLOCKS - 1) {
            __threadfence();
            out[0] = sqrtf(atomicAdd(lossacc, 0.0f));  // atomic read
        }
    }
}

// ---------------------------------------------------------------------- host
extern "C" void kernel_launch(void* const* d_in, const int* in_sizes, int n_in,
                              void* d_out, int out_size, void* d_ws, size_t ws_size,
                              hipStream_t stream) {
    const float* E = (const float*)d_in[0];
    // d_in[1] (label) unused by the reference math.
    float* out = (float*)d_out;
    float* ws = (float*)d_ws;

    cast_t_kernel<<<dim3(4, 32), 256, 0, stream>>>(E, ws);
    gram_kernel<<<dim3(NT, CHUNKS), 256, 0, stream>>>(ws);
    finalize_kernel<<<FIN_BLOCKS, 256, 0, stream>>>(ws, out);
}

// Round 6
// 76.027 us; speedup vs baseline: 1.2101x; 1.0974x over previous
//
#include <hip/hip_runtime.h>
#include <math.h>

typedef unsigned int uint32;
typedef unsigned short u16;
typedef __bf16 bf16x8 __attribute__((ext_vector_type(8)));
typedef float f32x16 __attribute__((ext_vector_type(16)));

#define BROWS 8192
#define WDIM 256
#define NT 3             // 128x128 tile pairs: t0=(0,0), t1=(0,1), t2=(1,1)
#define CHUNKS 64        // 64 * 128 rows = 8192
#define TILE_ELEMS 16384
#define FIN_BLOCKS 192   // 192*256 = 49152 = NT*TILE_ELEMS

// ws float layout:
// [0 .. 16383]   colsum_part[64 chunks][256] (plain stores by t1 blocks)
// [16384]        lossacc  (zeroed inside gram kernel; ordered by kernel boundary)
// [16385]        done u32
// [16640 .. ]    partials bf16: NT*CHUNKS*TILE_ELEMS u16 (6.3 MB)
#define WS_LOSS 16384
#define WS_DONE 16385
#define WS_PART 16640

__device__ __forceinline__ uint32 pack2bf(float lo, float hi) {
    uint32 a = __float_as_uint(lo), b = __float_as_uint(hi);
    a = (a + 0x7FFFu + ((a >> 16) & 1u)) >> 16;   // RNE fp32->bf16
    b = (b + 0x7FFFu + ((b >> 16) & 1u)) >> 16;
    return (a & 0xFFFFu) | (b << 16);
}
__device__ __forceinline__ u16 f2bf(float x) {
    uint32 a = __float_as_uint(x);
    return (u16)((a + 0x7FFFu + ((a >> 16) & 1u)) >> 16);
}
__device__ __forceinline__ float bflo(uint32 v) { return __uint_as_float(v << 16); }
__device__ __forceinline__ float bfhi(uint32 v) { return __uint_as_float(v & 0xFFFF0000u); }

// LDS layout: U[col][krp] (krp = k/2, 64 dwords per col), 16B-group XOR swizzle:
// dword idx = col*64 + ((grp ^ (col&15))<<2) + (krp&3), grp = krp>>2.
// Keeps every 4-dword logical group 16B-contiguous (b128 reads legal) while
// spreading banks: fragment reads land at <=4-way conflict (~1.58x, small traffic).
__device__ __forceinline__ int uswz(int col, int krp) {
    return col * 64 + ((((krp >> 2) ^ (col & 15)) << 2) | (krp & 3));
}

// -------------------- fused cast + MFMA gram (+ colsum on t1 blocks) --------
// grid (NT, CHUNKS), 256 thr = 4 waves. Block (t,c) loads E rows
// [c*128,(c+1)*128) x needed cols (block-LOCAL dependency -> no global E_t).
__global__ __launch_bounds__(256)
void gram_fused(const float* __restrict__ E, float* __restrict__ ws) {
    __shared__ uint32 U[WDIM * 64];            // 64 KB
    const int t = blockIdx.x, c = blockIdx.y;
    const int tid = threadIdx.x;
    const int ncg = (t == 1) ? 4 : 2;          // 64-col groups held in U
    const int gcol0 = (t == 2) ? 128 : 0;      // global col of U local col 0
    const int row0 = c * 128;
    const int c4 = tid & 15, rp = tid >> 4;

    if (t == 0 && c == 0 && tid < 2) ws[WS_LOSS + tid] = 0.0f;  // lossacc+done

    for (int cg = 0; cg < ncg; ++cg) {
        const float* Eb = E + (size_t)row0 * WDIM + gcol0 + cg * 64;
        float4 fa[4], fb[4];
        #pragma unroll
        for (int p = 0; p < 4; ++p) {          // rowpairs rp+16p -> rows 2*,2*+1
            const int r0 = 2 * (rp + 16 * p);
            fa[p] = *(const float4*)(Eb + (size_t)r0 * WDIM + c4 * 4);
            fb[p] = *(const float4*)(Eb + (size_t)(r0 + 1) * WDIM + c4 * 4);
        }
        #pragma unroll
        for (int p = 0; p < 4; ++p) {
            const int krp = rp + 16 * p;
            const int colb = cg * 64 + c4 * 4;
            const float av[4] = {fa[p].x, fa[p].y, fa[p].z, fa[p].w};
            const float bv[4] = {fb[p].x, fb[p].y, fb[p].z, fb[p].w};
            #pragma unroll
            for (int i = 0; i < 4; ++i)
                U[uswz(colb + i, krp)] = pack2bf(av[i], bv[i]);
        }
    }
    __syncthreads();                           // the only barrier

    if (t == 1) {                              // colsum (bf16-rounded; err ~4e-5)
        const int col = tid;                   // all 256 cols live in U here
        float s = 0.f;
        #pragma unroll
        for (int g = 0; g < 16; ++g) {
            const uint4 v = *(const uint4*)&U[col * 64 + ((g ^ (col & 15)) << 2)];
            s += bflo(v.x) + bfhi(v.x) + bflo(v.y) + bfhi(v.y)
               + bflo(v.z) + bfhi(v.z) + bflo(v.w) + bfhi(v.w);
        }
        ws[c * WDIM + col] = s;                // per-chunk slot, no init needed
    }

    // MFMA: wave w -> tile rows [32w,32w+32); local col = global - gcol0.
    const int w = tid >> 6, l = tid & 63, lm = l & 31;
    const int bBase = (t == 1) ? 128 : 0;
    const int colA = w * 32 + lm;

    f32x16 acc[4];
    #pragma unroll
    for (int n = 0; n < 4; ++n)
        #pragma unroll
        for (int r = 0; r < 16; ++r) acc[n][r] = 0.f;

    #pragma unroll
    for (int s8 = 0; s8 < 8; ++s8) {           // K = 128 = 8 steps of 16
        const int grp = 2 * s8 + (l >> 5);     // logical 16B group = k/8
        const bf16x8 a = *(const bf16x8*)&U[colA * 64 + ((grp ^ (colA & 15)) << 2)];
        #pragma unroll
        for (int n = 0; n < 4; ++n) {
            const int colB = bBase + n * 32 + lm;
            const bf16x8 b = *(const bf16x8*)&U[colB * 64 + ((grp ^ (colB & 15)) << 2)];
            acc[n] = __builtin_amdgcn_mfma_f32_32x32x16_bf16(a, b, acc[n], 0, 0, 0);
        }
    }

    // bf16 partials (halves finalize traffic; adds ~4e-4 to loss, 100x margin).
    // C/D layout (m74/m101): col = lane&31, row = (r&3)+8*(r>>2)+4*(lane>>5)
    u16* part = (u16*)(ws + WS_PART);
    u16* dst = part + ((size_t)c * NT + t) * TILE_ELEMS;
    const int rbase = 32 * w + 4 * (l >> 5);
    #pragma unroll
    for (int n = 0; n < 4; ++n)
        #pragma unroll
        for (int r = 0; r < 16; ++r) {
            const int row = rbase + (r & 3) + 8 * (r >> 2);
            dst[row * 128 + n * 32 + lm] = f2bf(acc[n][r]);
        }
}

// ----------------------------------------------- finalize loss + sqrt fused
__global__ __launch_bounds__(256)
void finalize_kernel(float* __restrict__ ws, float* __restrict__ out) {
    __shared__ float mu[WDIM];
    __shared__ float red[4];
    const u16* part = (const u16*)(ws + WS_PART);
    float* lossacc = ws + WS_LOSS;
    unsigned* done = (unsigned*)(ws + WS_DONE);
    const int tid = threadIdx.x;

    {   // reduce the 64 per-chunk colsum slots -> mu
        float s = 0.f;
        #pragma unroll 8
        for (int c = 0; c < CHUNKS; ++c) s += ws[c * WDIM + tid];
        mu[tid] = s * (1.0f / (float)BROWS);
    }
    __syncthreads();

    const int e = blockIdx.x * 256 + tid;            // 0..49151
    const int t = e >> 14, local = e & 16383;
    const int ti = (t == 2) ? 1 : 0;
    const int tj = (t == 0) ? 0 : 1;
    const int i = ti * 128 + (local >> 7);
    const int j = tj * 128 + (local & 127);

    float g = 0.f;
    #pragma unroll 8
    for (int c = 0; c < CHUNKS; ++c)
        g += bflo((uint32)part[((size_t)c * NT + t) * TILE_ELEMS + local]);

    const float diff = g * (1.0f / (float)BROWS) - mu[i] * mu[j] - ((i == j) ? 1.0f : 0.0f);
    float v = ((t == 1) ? 2.0f : 1.0f) * diff * diff;

    #pragma unroll
    for (int o = 32; o > 0; o >>= 1) v += __shfl_down(v, o, 64);
    if ((tid & 63) == 0) red[tid >> 6] = v;
    __syncthreads();
    if (tid == 0) {
        atomicAdd(lossacc, red[0] + red[1] + red[2] + red[3]);
        __threadfence();
        const unsigned old = atomicAdd(done, 1u);
        if (old == FIN_BLOCKS - 1) {
            __threadfence();
            out[0] = sqrtf(atomicAdd(lossacc, 0.0f));  // atomic read
        }
    }
}

// ---------------------------------------------------------------------- host
extern "C" void kernel_launch(void* const* d_in, const int* in_sizes, int n_in,
                              void* d_out, int out_size, void* d_ws, size_t ws_size,
                              hipStream_t stream) {
    const float* E = (const float*)d_in[0];
    // d_in[1] (label) unused by the reference math.
    float* out = (float*)d_out;
    float* ws = (float*)d_ws;

    gram_fused<<<dim3(NT, CHUNKS), 256, 0, stream>>>(E, ws);
    finalize_kernel<<<FIN_BLOCKS, 256, 0, stream>>>(ws, out);
}